// Round 6
// baseline (132.653 us; speedup 1.0000x reference)
//
#include <hip/hip_runtime.h>
#include <hip/hip_bf16.h>

// KANLayer: out = (relu(x[:,:,None]*W1+b1) . W2 + b2) @ Wc^T + bc
// B=16384, D=256, H=64, O=256.
// v3: weights read global-direct per-lane (L2-resident, lane owns row d=c*64+dl)
//     -> LDS = 16KB uT only -> 4 blocks/CU (was 2), 1 barrier (was 8).
//     Wc pre-converted to bf16 in d_ws by a tiny prep kernel.
#define B_N 16384
#define D_N 256
#define H_N 64
#define O_N 256

typedef __attribute__((ext_vector_type(8))) short short8;
typedef __attribute__((ext_vector_type(4))) short short4v;
typedef __attribute__((ext_vector_type(4))) float f32x4;

// f32 -> bf16 bits, round-to-nearest-even (finite inputs only)
static __device__ __forceinline__ unsigned short f2bf(float f) {
  unsigned int v = __float_as_uint(f);
  unsigned int r = (v + 0x7fffu + ((v >> 16) & 1u)) >> 16;
  return (unsigned short)r;
}

__global__ void wc_prep(const float* __restrict__ Wc, unsigned short* __restrict__ o) {
  const int i = (blockIdx.x * 256 + threadIdx.x) * 4;
  const f32x4 v = *reinterpret_cast<const f32x4*>(Wc + i);
  short4v s;
#pragma unroll
  for (int q = 0; q < 4; ++q) s[q] = (short)f2bf(v[q]);
  *reinterpret_cast<short4v*>(o + i) = s;
}

template <bool WCB>
__global__ __launch_bounds__(256, 4) void kan_fused(
    const float* __restrict__ x, const float* __restrict__ W1,
    const float* __restrict__ b1, const float* __restrict__ W2,
    const float* __restrict__ b2, const float* __restrict__ Wc,
    const unsigned short* __restrict__ Wcb, const float* __restrict__ bc,
    float* __restrict__ out) {
  __shared__ unsigned short uT[32 * 256];  // u tile [row][d] bf16, XOR-swizzled, 16KB

  const int tid = threadIdx.x;
  const int dl  = tid & 63;   // lane
  const int wv  = tid >> 6;   // wave id 0..3
  const int b0  = blockIdx.x * 32;

  // ---------------- phase 1: u[b0..b0+31][0..255] ----------------
  // Lane dl handles feature row d = c*64+dl; weights streamed global-direct
  // (192KB total, L2-resident, 16B/lane dwordx4 at immediate offsets).
#pragma unroll
  for (int c = 0; c < 4; ++c) {
    const int d0   = c * 64;
    const int drow = d0 + dl;
    const float* w1p = W1 + drow * H_N;
    const float* b1p = b1 + drow * H_N;
    const float* w2p = W2 + drow * H_N;

    float xv[8], acc[8];
#pragma unroll
    for (int r = 0; r < 8; ++r) {
      xv[r]  = x[(b0 + wv * 8 + r) * D_N + drow];  // 256B coalesced per r
      acc[r] = 0.f;
    }
#pragma unroll
    for (int h0 = 0; h0 < H_N; h0 += 4) {
      const f32x4 a4 = *reinterpret_cast<const f32x4*>(w1p + h0);
      const f32x4 c4 = *reinterpret_cast<const f32x4*>(b1p + h0);
      const f32x4 w4 = *reinterpret_cast<const f32x4*>(w2p + h0);
#pragma unroll
      for (int k = 0; k < 4; ++k) {
#pragma unroll
        for (int r = 0; r < 8; ++r) {
          float t = fmaf(xv[r], a4[k], c4[k]);
          t = fmaxf(t, 0.f);
          acc[r] = fmaf(t, w4[k], acc[r]);
        }
      }
    }
    const float bias = b2[drow];
    // uT chunk-writes are disjoint 128B windows per row (swizzle XORs bits 4-6
    // only) -> no inter-chunk barrier needed; one barrier before phase 2.
#pragma unroll
    for (int r = 0; r < 8; ++r) {
      const int row = wv * 8 + r;
      int byte = row * 512 + drow * 2;
      byte ^= (row & 7) << 4;  // T2 swizzle for conflict-free MFMA A-reads
      *reinterpret_cast<unsigned short*>(reinterpret_cast<char*>(uT) + byte) =
          f2bf(acc[r] + bias);
    }
  }
  __syncthreads();

  // ---------------- phase 2: out[b0..b0+31][:] = u @ Wc^T + bc ----------------
  // wave wv owns N-slice [wv*64, wv*64+64); wave tile M=32 x N=64 -> acc2[2][4]
  const int n0   = wv * 64;
  const int mrow = dl & 15;
  const int kgrp = dl >> 4;  // 0..3

  f32x4 acc2[2][4];
#pragma unroll
  for (int i = 0; i < 2; ++i)
#pragma unroll
    for (int j = 0; j < 4; ++j) acc2[i][j] = (f32x4)(0.f);

#pragma unroll
  for (int ks = 0; ks < 8; ++ks) {
    const int k0 = ks * 32 + kgrp * 8;  // first bf16 k this lane consumes
    // A frags from swizzled LDS u-tile: lane holds u[row=i*16+mrow][k0..k0+7]
    short8 afrag[2];
#pragma unroll
    for (int i = 0; i < 2; ++i) {
      const int row = i * 16 + mrow;
      int byte = row * 512 + k0 * 2;
      byte ^= (row & 7) << 4;
      afrag[i] = *reinterpret_cast<const short8*>(
          reinterpret_cast<const char*>(uT) + byte);
    }
    // B frags: Wc[n][k0..k0+7] (L2-resident)
    short8 bfrag[4];
#pragma unroll
    for (int j = 0; j < 4; ++j) {
      const int n = n0 + j * 16 + mrow;
      if (WCB) {
        bfrag[j] = *reinterpret_cast<const short8*>(Wcb + n * D_N + k0);
      } else {
        const float* p = Wc + n * D_N + k0;
        const f32x4 lo = *reinterpret_cast<const f32x4*>(p);
        const f32x4 hi = *reinterpret_cast<const f32x4*>(p + 4);
        short8 bf;
#pragma unroll
        for (int q = 0; q < 4; ++q) bf[q] = (short)f2bf(lo[q]);
#pragma unroll
        for (int q = 0; q < 4; ++q) bf[q + 4] = (short)f2bf(hi[q]);
        bfrag[j] = bf;
      }
    }
#pragma unroll
    for (int i = 0; i < 2; ++i)
#pragma unroll
      for (int j = 0; j < 4; ++j)
        acc2[i][j] = __builtin_amdgcn_mfma_f32_16x16x32_bf16(
            afrag[i], bfrag[j], acc2[i][j], 0, 0, 0);
  }

  // epilogue: C/D map col=lane&15, row=4*(lane>>4)+q  (m89-verified)
#pragma unroll
  for (int j = 0; j < 4; ++j) {
    const int colg = n0 + j * 16 + mrow;
    const float bcv = bc[colg];
#pragma unroll
    for (int i = 0; i < 2; ++i) {
#pragma unroll
      for (int q = 0; q < 4; ++q) {
        const int rowg = b0 + i * 16 + kgrp * 4 + q;
        out[rowg * O_N + colg] = acc2[i][j][q] + bcv;
      }
    }
  }
}

extern "C" void kernel_launch(void* const* d_in, const int* in_sizes, int n_in,
                              void* d_out, int out_size, void* d_ws, size_t ws_size,
                              hipStream_t stream) {
  const float* x  = (const float*)d_in[0];
  const float* W1 = (const float*)d_in[1];
  const float* b1 = (const float*)d_in[2];
  const float* W2 = (const float*)d_in[3];
  const float* b2 = (const float*)d_in[4];
  const float* Wc = (const float*)d_in[5];
  const float* bc = (const float*)d_in[6];
  float* out = (float*)d_out;

  if (ws_size >= (size_t)(O_N * D_N * sizeof(unsigned short))) {
    unsigned short* Wcb = (unsigned short*)d_ws;
    wc_prep<<<dim3(O_N * D_N / (256 * 4)), dim3(256), 0, stream>>>(Wc, Wcb);
    kan_fused<true><<<dim3(B_N / 32), dim3(256), 0, stream>>>(
        x, W1, b1, W2, b2, Wc, Wcb, bc, out);
  } else {
    kan_fused<false><<<dim3(B_N / 32), dim3(256), 0, stream>>>(
        x, W1, b1, W2, b2, Wc, (const unsigned short*)nullptr, bc, out);
  }
}